// Round 5
// baseline (669.104 us; speedup 1.0000x reference)
//
#include <hip/hip_runtime.h>
#include <hip/hip_bf16.h>

// SpiralFC: out[b,o,y,x] = sum_c W[o,c] * x[b, y+dy[c], x+dx[c], c] + bias[o]
// Integer shifts (round() in reference) -> pure shift with zero padding.
//
//   K1 shift_halo_kernel : Xs[m][c] = bf16(x[b, y+dy[c], x+dx[c], c])  (ws)
//                          + Wb[o][c] = bf16(W[o][c])                  (ws)
//   K2 gemm_kernel       : out^T[o][m] = Wb[o][:] . Xs[m][:] + bias[o]
//
// R5 shift (halo design): R4's lane=channel gather split every wave-load
// into ~15-20 tiny dy-row segments (8M L2 transactions -> TA-rate bound at
// 1.6TB/s, occupancy didn't help). New: block = (image, 8-row group,
// 32-ch slice); stage 22 rows (8+7+7 halo) STRAIGHT (each 128B line is
// exactly one slice-row piece -> clean 128B segments); dy AND dx applied
// on the LDS READ address (2-way bank alias = free); stores coalesced.
// Upper 256 channels have zero shift -> pure float4 streaming copy.
// Halo re-reads are XCD-local L2 hits (chunked swizzle, 1792%8==0).
//
// R5 gemm (2-phase dbuf, T3-minimum): old loop did stage -> drain-barrier
// -> compute -> barrier: HBM fetch fully serialized with MFMA (MfmaUtil
// 16%, 110us of stall). New: double-buffer LDS, issue next tile's
// global_load_lds BEFORE computing current tile, ONE barrier per K-tile.

#define HD 56
#define WD 56
#define HW 3136
#define CCH 512
#define NBATCH 32
#define MTOT (NBATCH * HW)          // 100352

#define BM 128
#define BN 128
#define BK 64

#define XS_ELEMS ((size_t)MTOT * CCH)
#define XS_BYTES (XS_ELEMS * 2)            // 102,760,448
#define WB_BYTES ((size_t)CCH * CCH * 2)   // 524,288

typedef __attribute__((ext_vector_type(8))) __bf16 bf16x8;
typedef __attribute__((ext_vector_type(4))) float f32x4;
typedef __attribute__((ext_vector_type(8))) unsigned short ushort8_t;

#define AS1 __attribute__((address_space(1)))
#define AS3 __attribute__((address_space(3)))

__device__ __forceinline__ unsigned short f2bf(float f) {
    __hip_bfloat16 h = __float2bfloat16(f);
    return __builtin_bit_cast(unsigned short, h);
}

__device__ __forceinline__ void load16_lds(const unsigned short* g, unsigned short* l) {
    __builtin_amdgcn_global_load_lds((const AS1 unsigned int*)g,
                                     (AS3 unsigned int*)l, 16, 0, 0);
}

// ---------------------------------------------------------------- K1: shift
// halo blocks: 32 images x 7 y-groups(8 rows) x 8 ch-slices(32 ch of lower 256)
#define HALO_BLOCKS (NBATCH * 7 * 8)          // 1792 (% 8 == 0)
#define COPY_BLOCKS 1792                      // upper-256-ch streaming copy
#define WGT_BLOCKS (CCH * CCH / 8 / 256)      // 128
#define SH_ROWS 22                            // 8 owned + 7 + 7 halo

__global__ __launch_bounds__(256) void shift_halo_kernel(
    const float* __restrict__ x,     // [B][H][W][C]
    const float* __restrict__ wgt,   // [O][C]
    const float* __restrict__ offs,  // [C][2]
    unsigned short* __restrict__ Xs, // [M][C] bf16
    unsigned short* __restrict__ Wb) // [O][C] bf16
{
    const int tid = threadIdx.x;
    const int bid0 = (int)blockIdx.x;

    if (bid0 >= HALO_BLOCKS + COPY_BLOCKS) {
        // weight convert: 8 floats / thread
        const int e = (bid0 - (HALO_BLOCKS + COPY_BLOCKS)) * 256 + tid;
        const float4* src = (const float4*)wgt + (size_t)e * 2;
        float4 a = src[0], b = src[1];
        ushort8_t o;
        o[0] = f2bf(a.x); o[1] = f2bf(a.y); o[2] = f2bf(a.z); o[3] = f2bf(a.w);
        o[4] = f2bf(b.x); o[5] = f2bf(b.y); o[6] = f2bf(b.z); o[7] = f2bf(b.w);
        *(ushort8_t*)(Wb + (size_t)e * 8) = o;
        return;
    }

    if (bid0 >= HALO_BLOCKS) {
        // upper 256 channels: zero shift -> streaming float4 copy/convert.
        // chunk = one float4 of the upper half: 64 chunks / pixel.
        const int cb = bid0 - HALO_BLOCKS;           // 0..1791
        const size_t e0 = (size_t)cb * 3584 + tid;   // 14 chunks/thread
#pragma unroll
        for (int bt = 0; bt < 2; bt++) {
            float4 v[7];
#pragma unroll
            for (int t = 0; t < 7; t++) {
                const size_t e = e0 + (size_t)(bt * 7 + t) * 256;
                const size_t px = e >> 6;
                const int cq = (int)(e & 63);
                v[t] = *(const float4*)(x + px * CCH + 256 + cq * 4);
            }
#pragma unroll
            for (int t = 0; t < 7; t++) {
                const size_t e = e0 + (size_t)(bt * 7 + t) * 256;
                const size_t px = e >> 6;
                const int cq = (int)(e & 63);
                ushort4 u;
                u.x = f2bf(v[t].x); u.y = f2bf(v[t].y);
                u.z = f2bf(v[t].z); u.w = f2bf(v[t].w);
                *(ushort4*)(Xs + px * CCH + 256 + cq * 4) = u;
            }
        }
        return;
    }

    // ---- halo shift for lower 256 channels ----
    // XCD-chunked swizzle (1792 % 8 == 0): consecutive logical blocks
    // (adjacent y-groups sharing halo rows) land on the same XCD L2.
    const int lb = (bid0 & 7) * (HALO_BLOCKS / 8) + (bid0 >> 3);
    const int b  = lb / 56;
    const int r  = lb - b * 56;
    const int g  = r >> 3;            // y-group 0..6
    const int s  = r & 7;             // channel-slice 0..7
    const int y0 = g * 8;
    const int c0 = s * 32;

    __shared__ unsigned short sH[SH_ROWS * WD * 32];  // 78,848 B

    // P1: stage 22 rows x 56 px x 32 ch, straight (no shift), zeros for
    // out-of-image rows. 154 elements/thread in 11 reg-batches of 14.
    const float* xb = x + (size_t)b * HW * CCH;
#pragma unroll
    for (int bt = 0; bt < 11; bt++) {
        float v[14];
#pragma unroll
        for (int t = 0; t < 14; t++) {
            const int e = (bt * 14 + t) * 256 + tid;
            const int rloc = e / 1792;
            const int rem  = e - rloc * 1792;
            const int yi = y0 - 7 + rloc;
            v[t] = ((unsigned)yi < (unsigned)HD)
                 ? xb[((size_t)yi * WD + (rem >> 5)) * CCH + c0 + (rem & 31)]
                 : 0.0f;
        }
#pragma unroll
        for (int t = 0; t < 14; t++) {
            const int e = (bt * 14 + t) * 256 + tid;
            sH[e] = f2bf(v[t]);
        }
    }
    __syncthreads();

    // P2: dy+dx applied on the LDS read address; global stores coalesced.
    const int ci = tid & 31;
    const int c  = c0 + ci;
    const int dy = (int)offs[2 * c];
    const int dx = (int)offs[2 * c + 1];
#pragma unroll 8
    for (int it = 0; it < 56; it++) {
        const int e = it * 256 + tid;        // 0..14335
        const int yloc = e / 1792;           // 0..7
        const int rem  = e - yloc * 1792;
        const int px   = rem >> 5;           // 0..55   (rem&31 == ci)
        const int yy_loc = yloc + 7 + dy;    // staged row idx, in [0,22)
        const int xs = px + dx;
        unsigned short u = 0;
        if ((unsigned)xs < (unsigned)WD)
            u = sH[(yy_loc * WD + xs) * 32 + ci];
        Xs[((size_t)b * HW + (size_t)(y0 + yloc) * WD + px) * CCH + c] = u;
    }
}

// ----------------------------------------------------------------- K2: GEMM
__global__ __launch_bounds__(256) void gemm_kernel(
    const unsigned short* __restrict__ Xs,   // [M][512] bf16
    const unsigned short* __restrict__ Wb,   // [512][512] bf16
    const float* __restrict__ bias,
    float* __restrict__ out)                 // [B][O][H][W]
{
    __shared__ unsigned short sW[2 * BM * BK];   // 32KB (double-buffered)
    __shared__ unsigned short sX[2 * BN * BK];   // 32KB
    __shared__ float sBias[BM];

    const int tid = threadIdx.x;
    // XCD-chunked swizzle (3136 % 8 == 0): the 4 o-siblings sharing one
    // Xs tile live on the same XCD L2.
    const int bid0 = (int)blockIdx.x;
    const int bid  = (bid0 & 7) * (3136 / 8) + (bid0 >> 3);
    const int ot = bid & 3;
    const int pt = bid >> 2;
    const int O0 = ot * BM;
    const int P0 = pt * BN;

    if (tid < BM) sBias[tid] = bias[O0 + tid];

    const int w   = tid >> 6;
    const int l   = tid & 63;
    const int q   = l >> 4;
    const int c16 = l & 15;
    const int wo  = w & 1;
    const int wm  = w >> 1;

    // XOR swizzle: lds chunk (row, slot) holds global k-chunk slot^(row&7)
    const int lc    = (l & 7) ^ ((l >> 3) & 7);   // staging gather chunk
    const int k7    = c16 & 7;
    const int slot0 = q ^ k7;                     // frag slot, s=0 (chunk q)
    const int slot1 = (4 + q) ^ k7;               // frag slot, s=1 (chunk 4+q)

    f32x4 acc[4][4];
#pragma unroll
    for (int i = 0; i < 4; i++)
#pragma unroll
        for (int j = 0; j < 4; j++) acc[i][j] = (f32x4)0.0f;

#define STAGE(pw, px_, kk_) do {                                              \
    _Pragma("unroll")                                                         \
    for (int i_ = 0; i_ < 4; i_++) {                                          \
        const int ib_  = w * 4 + i_;                                          \
        const int row_ = ib_ * 8 + (l >> 3);                                  \
        load16_lds(Wb + (size_t)(O0 + row_) * CCH + (kk_) + lc * 8,           \
                   (pw) + ib_ * 512);                                         \
        load16_lds(Xs + (size_t)(P0 + row_) * CCH + (kk_) + lc * 8,           \
                   (px_) + ib_ * 512);                                        \
    }                                                                         \
} while (0)

#define COMPUTE(pw, px_) do {                                                 \
    _Pragma("unroll")                                                         \
    for (int s_ = 0; s_ < 2; s_++) {                                          \
        const int slot_ = s_ ? slot1 : slot0;                                 \
        bf16x8 pa[4], pb[4];                                                  \
        _Pragma("unroll")                                                     \
        for (int i_ = 0; i_ < 4; i_++)                                        \
            pa[i_] = *(const bf16x8*)&(pw)[(wo * 64 + i_ * 16 + c16) * BK     \
                                           + slot_ * 8];                      \
        _Pragma("unroll")                                                     \
        for (int j_ = 0; j_ < 4; j_++)                                        \
            pb[j_] = *(const bf16x8*)&(px_)[(wm * 64 + j_ * 16 + c16) * BK    \
                                            + slot_ * 8];                     \
        _Pragma("unroll")                                                     \
        for (int i_ = 0; i_ < 4; i_++)                                        \
            _Pragma("unroll")                                                 \
            for (int j_ = 0; j_ < 4; j_++)                                    \
                acc[i_][j_] = __builtin_amdgcn_mfma_f32_16x16x32_bf16(        \
                    pa[i_], pb[j_], acc[i_][j_], 0, 0, 0);                    \
    }                                                                         \
} while (0)

    // prologue: tile 0 -> buffer 0
    STAGE(sW, sX, 0);
    __syncthreads();   // compiler drains vmcnt(0) here

    // 2-phase pipeline: stage t+1 into the other buffer, compute t,
    // ONE barrier per K-tile (drain covers the just-issued loads).
#pragma unroll
    for (int t = 0; t < 8; t++) {
        unsigned short* cw = sW + (t & 1) * (BM * BK);
        unsigned short* cx = sX + (t & 1) * (BN * BK);
        unsigned short* nw = sW + ((t & 1) ^ 1) * (BM * BK);
        unsigned short* nx = sX + ((t & 1) ^ 1) * (BN * BK);
        if (t < 7) STAGE(nw, nx, (t + 1) * BK);
        COMPUTE(cw, cx);
        __syncthreads();
    }

    // epilogue: D[row=q*4+r][col=c16]; lanes 0..15 sweep consecutive pixels
#pragma unroll
    for (int j = 0; j < 4; j++) {
        const int g = P0 + wm * 64 + j * 16 + c16;
        const int b = g / HW;
        const int p = g - b * HW;
        float* obase = out + (size_t)b * CCH * HW + p;
#pragma unroll
        for (int i = 0; i < 4; i++) {
#pragma unroll
            for (int r = 0; r < 4; r++) {
                const int o_l = wo * 64 + i * 16 + q * 4 + r;
                obase[(size_t)(O0 + o_l) * HW] = acc[i][j][r] + sBias[o_l];
            }
        }
    }
#undef STAGE
#undef COMPUTE
}

// ------------------------------------------------------- fallback (fused R1)
#define LDK 72
__global__ __launch_bounds__(256) void spiralfc_fused(
    const float* __restrict__ x, const float* __restrict__ wgt,
    const float* __restrict__ bias, const float* __restrict__ offs,
    float* __restrict__ out)
{
    __shared__ unsigned short sW[BM * LDK];
    __shared__ unsigned short sX[BN * LDK];
    __shared__ int sDy[CCH];
    __shared__ int sDx[CCH];
    __shared__ float sBias[BM];

    const int tid = threadIdx.x;
    const int bid = blockIdx.x;
    const int O0 = (bid & 3) * BM;
    const int P0 = (bid >> 2) * BN;

    for (int k = tid; k < CCH; k += 256) {
        sDy[k] = (int)offs[2 * k];
        sDx[k] = (int)offs[2 * k + 1];
    }
    if (tid < BM) sBias[tid] = bias[O0 + tid];

    const int w = tid >> 6, l = tid & 63, q = l >> 4, c16 = l & 15;
    const int wo = w & 1, wm = w >> 1;

    f32x4 acc[4][4];
#pragma unroll
    for (int i = 0; i < 4; i++)
#pragma unroll
        for (int j = 0; j < 4; j++) acc[i][j] = (f32x4)0.0f;

    const int kcW = tid & 15, orW = tid >> 4;
    __syncthreads();

    for (int kk = 0; kk < CCH; kk += BK) {
#pragma unroll
        for (int ps = 0; ps < 8; ps++) {
            const int o = ps * 16 + orW;
            const float4 wv = *(const float4*)(wgt + (size_t)(O0 + o) * CCH + kk + kcW * 4);
            ushort4 uv;
            uv.x = f2bf(wv.x); uv.y = f2bf(wv.y); uv.z = f2bf(wv.z); uv.w = f2bf(wv.w);
            *(ushort4*)&sW[o * LDK + kcW * 4] = uv;
        }
#pragma unroll 4
        for (int ps = 0; ps < 32; ps++) {
            const int m = ps * 4 + w;
            const int g = P0 + m;
            const int b = g / HW;
            const int p = g - b * HW;
            const int y = p / WD;
            const int xx = p - y * WD;
            const int k = kk + l;
            const int yy = y + sDy[k];
            const int xs = xx + sDx[k];
            float v = 0.0f;
            if ((unsigned)yy < (unsigned)HD && (unsigned)xs < (unsigned)WD)
                v = x[((size_t)b * HW + yy * WD + xs) * CCH + k];
            sX[m * LDK + l] = f2bf(v);
        }
        __syncthreads();
#pragma unroll
        for (int s = 0; s < 2; s++) {
            bf16x8 af[4], bf[4];
#pragma unroll
            for (int i = 0; i < 4; i++)
                af[i] = *(const bf16x8*)&sW[(wo * 64 + i * 16 + c16) * LDK + s * 32 + q * 8];
#pragma unroll
            for (int j = 0; j < 4; j++)
                bf[j] = *(const bf16x8*)&sX[(wm * 64 + j * 16 + c16) * LDK + s * 32 + q * 8];
#pragma unroll
            for (int i = 0; i < 4; i++)
#pragma unroll
                for (int j = 0; j < 4; j++)
                    acc[i][j] = __builtin_amdgcn_mfma_f32_16x16x32_bf16(
                        af[i], bf[j], acc[i][j], 0, 0, 0);
        }
        __syncthreads();
    }
#pragma unroll
    for (int j = 0; j < 4; j++) {
        const int g = P0 + wm * 64 + j * 16 + c16;
        const int b = g / HW;
        const int p = g - b * HW;
        float* obase = out + (size_t)b * CCH * HW + p;
#pragma unroll
        for (int i = 0; i < 4; i++)
#pragma unroll
            for (int r = 0; r < 4; r++) {
                const int o_l = wo * 64 + i * 16 + q * 4 + r;
                obase[(size_t)(O0 + o_l) * HW] = acc[i][j][r] + sBias[o_l];
            }
    }
}

extern "C" void kernel_launch(void* const* d_in, const int* in_sizes, int n_in,
                              void* d_out, int out_size, void* d_ws, size_t ws_size,
                              hipStream_t stream) {
    const float* x    = (const float*)d_in[0];
    const float* wgt  = (const float*)d_in[1];
    const float* bias = (const float*)d_in[2];
    const float* offs = (const float*)d_in[3];
    float* out = (float*)d_out;

    if (ws_size >= XS_BYTES + WB_BYTES) {
        unsigned short* Xs = (unsigned short*)d_ws;
        unsigned short* Wb = (unsigned short*)((char*)d_ws + XS_BYTES);
        shift_halo_kernel<<<dim3(HALO_BLOCKS + COPY_BLOCKS + WGT_BLOCKS),
                            dim3(256), 0, stream>>>(x, wgt, offs, Xs, Wb);
        gemm_kernel<<<dim3(3136), dim3(256), 0, stream>>>(Xs, Wb, bias, out);
    } else {
        spiralfc_fused<<<dim3(3136), dim3(256), 0, stream>>>(x, wgt, bias, offs, out);
    }
}